// Round 5
// baseline (146.009 us; speedup 1.0000x reference)
//
#include <hip/hip_runtime.h>
#include <math.h>

#define HOP     128
#define NSLOTS  256
#define FPW     4      // frames per wave-chain: 8192 chains / 2048 blocks = full residency
#define PI_F    3.14159265358979323846f
#define PI2_F   1.57079632679489661923f
#define K8      0.70710678118654752440f

// Zero-instruction ordering fence for intra-wave LDS cross-lane handoffs.
#define LDS_FENCE() do { __asm__ volatile("" ::: "memory"); \
                         __builtin_amdgcn_wave_barrier(); } while (0)

// Packed-FP32 complex: ext_vector_type(2) makes LLVM emit v_pk_{add,mul,fma}_f32
// (full-rate dual FP32 on gfx90a+). Every packed op is the same IEEE op in the
// same order as the old scalar code (fma by +/-1 is an exact add/sub;
// (-K8)*x == -(K8*x)), so results stay bit-identical (absmax 0.0).
typedef float f2 __attribute__((ext_vector_type(2)));

__device__ __forceinline__ f2 cmul(f2 a, f2 b){   // a*b
    f2 m = a.yy * b.yx;                            // {ay*by, ay*bx}
    return __builtin_elementwise_fma(a.xx, b, f2{-m.x, m.y});
    // lo: ax*bx - ay*by   hi: ax*by + ay*bx   (== old scalar cmul)
}
__device__ __forceinline__ f2 cmulc(f2 a, f2 b){  // a*conj(b)
    f2 m = a.yx * b.yy;                            // {ay*by, ax*by}
    return __builtin_elementwise_fma(a, b.xx, f2{m.x, -m.y});
    // lo: ax*bx + ay*by   hi: ay*bx - ax*by   (== old scalar cmulc)
}

// |atan2(im,re)| in [0,pi] — scalar (cmp/min/max/div don't pack), unchanged.
__device__ __forceinline__ float abs_angle(float re, float im) {
    float a = fabsf(im), b = fabsf(re);
    float mn = fminf(a, b), mx = fmaxf(a, b);
    float t = __fdividef(mn, fmaxf(mx, 1e-37f));
    float t2 = t * t;
    float p = fmaf(t2, -0.0117212f, 0.05265332f);
    p = fmaf(t2, p, -0.11643287f);
    p = fmaf(t2, p, 0.19354346f);
    p = fmaf(t2, p, -0.33262347f);
    p = fmaf(t2, p, 0.99997726f);
    float r = t * p;
    r = (a > b) ? (PI2_F - r) : r;
    r = (re < 0.f) ? (PI_F - r) : r;
    return r;
}

// In-register 8-point DFT, natural-order output, packed-f32 form.
__device__ __forceinline__ void dft8(f2 v[8]) {
    const f2 pm = {1.f, -1.f};
    f2 a0=v[0]+v[4], a1=v[1]+v[5], a2=v[2]+v[6], a3=v[3]+v[7];
    f2 b0=v[0]-v[4], b1=v[1]-v[5], b2=v[2]-v[6], b3=v[3]-v[7];
    // b1 *= e^{-i pi/4}: {K8*(x+y), K8*(y-x)}
    b1 = K8 * __builtin_elementwise_fma(b1.yx, pm, b1);   // fma(+-1) == exact add/sub
    // b2 *= -i: {y, -x}
    b2 = b2.yx * pm;
    // b3 *= e^{-3i pi/4}: {K8*(y-x), -K8*(x+y)}
    {
        f2 t = __builtin_elementwise_fma(b3.yx, pm, b3);  // {x+y, y-x}
        b3 = f2{K8, -K8} * t.yx;
    }
    f2 c0=a0+a2, c2=a0-a2;
    f2 c1=a1+a3, c3=a1-a3; c3 = c3.yx * pm;               // *-i
    f2 d0=b0+b2, d2=b0-b2;
    f2 d1=b1+b3, d3=b1-b3; d3 = d3.yx * pm;               // *-i
    v[0]=c0+c1; v[4]=c0-c1;
    v[2]=c2+c3; v[6]=c2-c3;
    v[1]=d0+d1; v[5]=d0-d1;
    v[3]=d2+d3; v[7]=d2-d3;
}

// Register budget (rounds 1-3 lesson): tw1 in VGPRs (14), tw2 in LDS,
// Hermitian partner via shuffle (no Z round-trip). Peak live ~58 < 64.
__global__ __launch_bounds__(256, 4) void phase_loss_kernel(
        const float* __restrict__ y, const float* __restrict__ g,
        float* __restrict__ acc, int* __restrict__ ticket,
        float* __restrict__ out, int T, int n_frames, float inv_count) {
    __shared__ f2 xch_all[4][512];   // XOR-swizzled transpose scratch (per wave)
    __shared__ f2 tw2_tab[7][8];     // W64^{(lane&7)*k}, k=1..7 (broadcast reads)
    __shared__ float wsum[3][4];
    __shared__ int is_last;

    const int tid  = threadIdx.x;
    const int lane = tid & 63;
    const int wid  = tid >> 6;
    const int l8   = lane & 7;
    f2* xch = xch_all[wid];

    // tw2 table once per block (same __sincosf expressions -> bit-identical).
    if (tid < 56) {
        const int k = (tid >> 3) + 1, l = tid & 7;
        float s, c;
        __sincosf(-(2.0f * PI_F / 64.0f) * (float)(l * k), &s, &c);
        tw2_tab[tid >> 3][l] = f2{c, s};
    }
    __syncthreads();

    // Stage-1 twiddles in registers (14 VGPRs), once per kernel.
    f2 tw1[7];
    #pragma unroll
    for (int k = 1; k < 8; ++k) {
        float s, c;
        __sincosf(-(2.0f * PI_F / 512.0f) * (float)(lane * k), &s, &c);
        tw1[k - 1] = f2{c, s};
    }

    float ip = 0.f, gd = 0.f, iaf = 0.f;
    f2 Cp[5];
    const int tmax_int = (T - 256) / HOP;   // frames [2, tmax_int] need no reflect
    const int ra1 = (lane >> 3) * 72 + (lane & 7);       // stage-1 read base, XOR (r<<3)
    const int ra2 = (lane >> 3) * 65 + (lane & 7) * 8;   // stage-2 read base, XOR r
    const int rsl = (lane + 63) & 63;                    // rotate-down-1 shuffle source
    const int rsh = (64 - lane) & 63;                    // Hermitian partner source lane
    const f2 pm = {1.f, -1.f};

    auto do_frame = [&](int t, bool accum, bool hp) {
        f2 v[8];
        const int base = t * HOP - 256 + lane;
        if (t >= 2 && t <= tmax_int) {       // fast path: no reflect clamps
            #pragma unroll
            for (int r = 0; r < 8; ++r) {
                int j = base + r * 64;
                v[r] = f2{y[j], g[j]};
            }
        } else {
            #pragma unroll
            for (int r = 0; r < 8; ++r) {
                int j = base + r * 64;
                j = (j < 0) ? -j : j;
                j = (j >= T) ? (2 * T - 2 - j) : j;
                v[r] = f2{y[j], g[j]};
            }
        }
        // stage 1: DFT8 over n2, twiddle W512^{lane*k} (registers)
        dft8(v);
        #pragma unroll
        for (int k = 1; k < 8; ++k) v[k] = cmul(v[k], tw1[k - 1]);
        LDS_FENCE();   // orders prev frame's stage-2 reads vs these writes
        #pragma unroll
        for (int k = 0; k < 8; ++k)
            xch[lane ^ (72 * k)] = v[k];
        LDS_FENCE();
        #pragma unroll
        for (int r = 0; r < 8; ++r)
            v[r] = xch[ra1 ^ (r << 3)];
        // stage 2: DFT8, twiddle W64^{(lane&7)*k} from LDS table (broadcast)
        dft8(v);
        #pragma unroll
        for (int k = 1; k < 8; ++k)
            v[k] = cmul(v[k], tw2_tab[k - 1][l8]);
        LDS_FENCE();
        #pragma unroll
        for (int k = 0; k < 8; ++k)
            xch[lane ^ (65 * k)] = v[k];
        LDS_FENCE();
        #pragma unroll
        for (int r = 0; r < 8; ++r)
            v[r] = xch[ra2 ^ r];
        // stage 3: DFT8 -> bin f = lane + 64*reg, full spectrum in regs
        dft8(v);
        // Hermitian partner Z[(512-f)&511] via shuffle, no LDS round-trip:
        // lane>=1: partner = v[7-jj] from lane 64-lane; lane==0: own v[(8-jj)&7].
        f2 Cc[5];
        #pragma unroll
        for (int jj = 0; jj < 5; ++jj) {
            float px = __shfl(v[7 - jj].x, rsh, 64);
            float py = __shfl(v[7 - jj].y, rsh, 64);
            px = (lane == 0) ? v[(8 - jj) & 7].x : px;
            py = (lane == 0) ? v[(8 - jj) & 7].y : py;
            f2 P = {px, py};
            f2 U = __builtin_elementwise_fma(P, pm, v[jj]);            // {ur, ui} = 2*Y
            f2 V = __builtin_elementwise_fma(P, f2{-1.f, 1.f}, v[jj]); // {vx, vy} = 2i*G
            f2 m = U.yy * V;                                           // {ui*vx, ui*vy}
            Cc[jj] = __builtin_elementwise_fma(U.xx, V.yx, f2{-m.x, m.y});
            // lo: ur*vy - ui*vx   hi: ur*vx + ui*vy   (C = Y*conj(G), x4)
        }
        if (accum) {
            // C[f-1] via lane-rotate shuffle; lane0 patched from previous jj.
            f2 rprev = {0.f, 0.f};
            #pragma unroll
            for (int jj = 0; jj < 4; ++jj) {
                f2 rj;
                rj.x = __shfl(Cc[jj].x, rsl, 64);
                rj.y = __shfl(Cc[jj].y, rsl, 64);
                f2 cmj = (jj > 0 && lane == 0) ? rprev : rj;
                f2 cc = Cc[jj];
                float aw = abs_angle(cc.x, cc.y);
                ip += aw;
                f2 qg = cmulc(cmj, cc);
                float gt = abs_angle(qg.x, qg.y);
                gd += (jj == 0 && lane == 0) ? aw : gt;   // gd row 0 term == ip term
                if (hp) {
                    f2 qi = cmulc(Cp[jj], cc);
                    iaf += abs_angle(qi.x, qi.y);
                } else {
                    iaf += aw;                             // iaf col 0 term == ip term
                }
                rprev = rj;
            }
            if (lane == 0) {   // bin 256
                f2 cc = Cc[4];
                float aw = abs_angle(cc.x, cc.y);
                ip += aw;
                f2 qg = cmulc(rprev, cc);                 // rprev = C[255] at lane 0
                gd += abs_angle(qg.x, qg.y);
                if (hp) {
                    f2 qi = cmulc(Cp[4], cc);
                    iaf += abs_angle(qi.x, qi.y);
                } else {
                    iaf += aw;
                }
            }
        }
        #pragma unroll
        for (int jj = 0; jj < 5; ++jj) Cp[jj] = Cc[jj];
    };

    const int chain   = (blockIdx.x << 2) | wid;        // 0 .. 4*gridDim.x-1
    const int nchains = (int)(gridDim.x << 2);
    const int t0 = chain * FPW;
    int tend = t0 + FPW;
    if (chain == nchains - 1) tend = n_frames;          // last chain takes remainder
    const bool havep = (t0 > 0);

    if (havep) do_frame(t0 - 1, false, false);
    #pragma unroll 2
    for (int t = t0; t < tend; ++t)
        do_frame(t, true, havep || (t > t0));

    // block reduce
    __syncthreads();
    for (int off = 32; off; off >>= 1) {
        ip  += __shfl_down(ip, off);
        gd  += __shfl_down(gd, off);
        iaf += __shfl_down(iaf, off);
    }
    if (lane == 0) { wsum[0][wid] = ip; wsum[1][wid] = gd; wsum[2][wid] = iaf; }
    __syncthreads();
    if (tid == 0) {
        const int slot = (int)(blockIdx.x & (NSLOTS - 1));
        atomicAdd(acc + 0 * NSLOTS + slot, wsum[0][0] + wsum[0][1] + wsum[0][2] + wsum[0][3]);
        atomicAdd(acc + 1 * NSLOTS + slot, wsum[1][0] + wsum[1][1] + wsum[1][2] + wsum[1][3]);
        atomicAdd(acc + 2 * NSLOTS + slot, wsum[2][0] + wsum[2][1] + wsum[2][2] + wsum[2][3]);
        __threadfence();
        is_last = (atomicAdd(ticket, 1) == (int)gridDim.x - 1);
    }
    __syncthreads();
    if (is_last) {
        for (int l = 0; l < 3; l++) {
            float vv = __hip_atomic_load(acc + l * NSLOTS + tid,
                                         __ATOMIC_RELAXED, __HIP_MEMORY_SCOPE_AGENT);
            for (int off = 32; off; off >>= 1) vv += __shfl_down(vv, off);
            if (lane == 0) wsum[l][wid] = vv;
        }
        __syncthreads();
        if (tid < 3)
            out[tid] = (wsum[tid][0] + wsum[tid][1] + wsum[tid][2] + wsum[tid][3]) * inv_count;
    }
}

extern "C" void kernel_launch(void* const* d_in, const int* in_sizes, int n_in,
                              void* d_out, int out_size, void* d_ws, size_t ws_size,
                              hipStream_t stream) {
    const float* y = (const float*)d_in[0];
    const float* g = (const float*)d_in[1];
    float* out = (float*)d_out;
    float* acc = (float*)d_ws;
    int* ticket = (int*)((char*)d_ws + 3 * NSLOTS * sizeof(float));
    const int T = in_sizes[0];
    const int n_frames = T / HOP + 1;                  // 32769
    int n_blocks = n_frames / (FPW * 4);               // 2048 (last chain absorbs rest)
    if (n_blocks < 1) n_blocks = 1;

    hipMemsetAsync(d_ws, 0, 3 * NSLOTS * sizeof(float) + sizeof(int), stream);
    const float inv_count = 1.0f / (257.0f * (float)n_frames);
    phase_loss_kernel<<<n_blocks, 256, 0, stream>>>(y, g, acc, ticket, out,
                                                    T, n_frames, inv_count);
}